// Round 2
// baseline (790.506 us; speedup 1.0000x reference)
//
#include <hip/hip_runtime.h>
#include <hip/hip_bf16.h>
#include <stdint.h>

// ---------------------------------------------------------------------------
// GroupedQueryAttention: hidden(B,S,4096) -> QKV proj -> RoPE -> causal GQA
// attention -> out proj.  B=2 S=2048 H=32 Hk=8 D=128.  bf16 MFMA internally.
// ---------------------------------------------------------------------------

#define HIDDEN 4096
#define NH 32
#define NKV 8
#define HD 128
#define SLEN 2048
#define BATCH 2

typedef __attribute__((ext_vector_type(8))) short bf16x8;
typedef __attribute__((ext_vector_type(4))) float f32x4;

__device__ __forceinline__ unsigned short f2bf(float f) {
  __hip_bfloat16 h = __float2bfloat16(f);  // RNE, compiler emits native cvt
  return *reinterpret_cast<unsigned short*>(&h);
}
__device__ __forceinline__ float bf2f(unsigned short h) {
  union { uint32_t u; float f; } v; v.u = ((uint32_t)h) << 16;
  return v.f;
}
__device__ __forceinline__ void gload_lds16(const void* g, void* l) {
  __builtin_amdgcn_global_load_lds(
      (const __attribute__((address_space(1))) unsigned int*)g,
      (__attribute__((address_space(3))) unsigned int*)l, 16, 0, 0);
}

// ---------------------------------------------------------------------------
// fp32 -> bf16 convert, 8 elems/thread. n = grid*2048 exactly.
// ---------------------------------------------------------------------------
__global__ __launch_bounds__(256) void cvt_f32_bf16(const float* __restrict__ in,
                                                    unsigned short* __restrict__ out) {
  size_t i = ((size_t)blockIdx.x * 256 + threadIdx.x) * 8;
  f32x4 a = *(const f32x4*)&in[i];
  f32x4 b = *(const f32x4*)&in[i + 4];
  bf16x8 o;
#pragma unroll
  for (int j = 0; j < 4; ++j) { o[j] = (short)f2bf(a[j]); o[4 + j] = (short)f2bf(b[j]); }
  *(bf16x8*)&out[i] = o;
}

// ---------------------------------------------------------------------------
// GEMM  C(M,N) = A(M,K) @ B(N,K)^T, bf16 in, OutT out.  m97 structure.
// ---------------------------------------------------------------------------
__device__ __forceinline__ void store_out(unsigned short* C, size_t i, float v) { C[i] = f2bf(v); }
__device__ __forceinline__ void store_out(float* C, size_t i, float v) { C[i] = v; }

template <typename OutT>
__global__ __launch_bounds__(256, 2)
void gemm_bt(const unsigned short* __restrict__ A, const unsigned short* __restrict__ B,
             OutT* __restrict__ C, int M, int N, int K) {
  __shared__ __align__(16) unsigned short Asm[128 * 32];
  __shared__ __align__(16) unsigned short Bsm[128 * 32];
  const int tid = threadIdx.x;
  const int lane = tid & 63, wid = tid >> 6;
  const int lr = lane & 15, lg = lane >> 4;
  const int wr = wid >> 1, wc = wid & 1;

  const int nbn = N >> 7;
  const int nwg = gridDim.x;
  int wg = (int)blockIdx.x;
  wg = (wg & 7) * (nwg >> 3) + (wg >> 3);  // XCD-aware swizzle (nwg%8==0)
  const int bm = wg / nbn, bn = wg % nbn;

  const unsigned short* Ab = A + (size_t)bm * 128 * K;
  const unsigned short* Bb = B + (size_t)bn * 128 * K;

  f32x4 acc[4][4] = {};

  const int c0 = tid, c1 = tid + 256;
  const int ar0 = c0 >> 2, ak0 = (c0 & 3) * 8;
  const int ar1 = c1 >> 2, ak1 = (c1 & 3) * 8;

  for (int kt = 0; kt < K; kt += 32) {
    __syncthreads();
    gload_lds16(Ab + (size_t)ar0 * K + kt + ak0, &Asm[c0 * 8]);
    gload_lds16(Ab + (size_t)ar1 * K + kt + ak1, &Asm[c1 * 8]);
    gload_lds16(Bb + (size_t)ar0 * K + kt + ak0, &Bsm[c0 * 8]);
    gload_lds16(Bb + (size_t)ar1 * K + kt + ak1, &Bsm[c1 * 8]);
    __syncthreads();

    bf16x8 af[4], bfr[4];
#pragma unroll
    for (int mi = 0; mi < 4; ++mi)
      af[mi] = *(const bf16x8*)&Asm[(wr * 64 + mi * 16 + lr) * 32 + lg * 8];
#pragma unroll
    for (int ni = 0; ni < 4; ++ni)
      bfr[ni] = *(const bf16x8*)&Bsm[(wc * 64 + ni * 16 + lr) * 32 + lg * 8];
#pragma unroll
    for (int mi = 0; mi < 4; ++mi)
#pragma unroll
      for (int ni = 0; ni < 4; ++ni)
        acc[mi][ni] = __builtin_amdgcn_mfma_f32_16x16x32_bf16(af[mi], bfr[ni], acc[mi][ni], 0, 0, 0);
  }

#pragma unroll
  for (int mi = 0; mi < 4; ++mi)
#pragma unroll
    for (int ni = 0; ni < 4; ++ni)
#pragma unroll
      for (int r = 0; r < 4; ++r) {
        size_t row = (size_t)bm * 128 + wr * 64 + mi * 16 + lg * 4 + r;
        size_t col = (size_t)bn * 128 + wc * 64 + ni * 16 + lr;
        store_out(C, row * N + col, acc[mi][ni][r]);
      }
}

// ---------------------------------------------------------------------------
// RoPE tables + apply
// ---------------------------------------------------------------------------
__global__ __launch_bounds__(256) void rope_tables(float* __restrict__ ct, float* __restrict__ st) {
  int idx = blockIdx.x * 256 + threadIdx.x;  // S*64
  int s = idx >> 6, j = idx & 63;
  float inv = exp2f(-(float)j * (13.287712379549449f / 64.f));
  float f = (float)s * inv;
  ct[idx] = cosf(f);
  st[idx] = sinf(f);
}

__global__ __launch_bounds__(256) void rope_apply(unsigned short* __restrict__ X,
                                                  const float* __restrict__ ct,
                                                  const float* __restrict__ st, int heads) {
  int idx = blockIdx.x * 256 + threadIdx.x;
  int jc = (idx & 7) * 8;
  int t2 = idx >> 3;
  int hh = t2 % heads;
  int row = t2 / heads;
  int s = row & (SLEN - 1);
  unsigned short* p = X + ((size_t)row * heads + hh) * HD;
  bf16x8 lo = *(bf16x8*)&p[jc];
  bf16x8 hi = *(bf16x8*)&p[64 + jc];
  bf16x8 nlo, nhi;
#pragma unroll
  for (int j = 0; j < 8; ++j) {
    float c = ct[s * 64 + jc + j];
    float sn = st[s * 64 + jc + j];
    float xl = bf2f((unsigned short)(lo[j]));
    float xh = bf2f((unsigned short)(hi[j]));
    nlo[j] = (short)f2bf(xl * c - xh * sn);
    nhi[j] = (short)f2bf(xh * c + xl * sn);
  }
  *(bf16x8*)&p[jc] = nlo;
  *(bf16x8*)&p[64 + jc] = nhi;
}

// ---------------------------------------------------------------------------
// V (B*S, NKV*HD) -> VT (B, NKV, HD, S)
// ---------------------------------------------------------------------------
__global__ __launch_bounds__(256) void transpose_v(const unsigned short* __restrict__ V,
                                                   unsigned short* __restrict__ VT) {
  __shared__ unsigned short tile[64][66];
  const int t = threadIdx.x;
  const int bs = blockIdx.x;
  const int bd = blockIdx.y;
  const int b = bs >> 5;
  const int s0 = (bs & 31) * 64;
  const int d0 = bd * 64;
#pragma unroll
  for (int it = 0; it < 2; ++it) {
    int si = (t >> 3) + it * 32;
    int dj = (t & 7) * 8;
    bf16x8 v = *(const bf16x8*)&V[(size_t)(b * SLEN + s0 + si) * (NKV * HD) + d0 + dj];
#pragma unroll
    for (int j = 0; j < 8; ++j) tile[si][dj + j] = (unsigned short)(v[j]);
  }
  __syncthreads();
#pragma unroll
  for (int it = 0; it < 2; ++it) {
    int di = (t >> 3) + it * 32;
    int sj = (t & 7) * 8;
    bf16x8 o;
#pragma unroll
    for (int j = 0; j < 8; ++j) o[j] = (short)tile[sj + j][di];
    int c = d0 + di;
    int kvh = c >> 7, d = c & 127;
    *(bf16x8*)&VT[(((size_t)b * NKV + kvh) * HD + d) * SLEN + s0 + sj] = o;
  }
}

// ---------------------------------------------------------------------------
// Flash attention, load-balanced + pipelined.
// Block = (pair, kvh, b) handles q-tiles {pair, 63-pair} (32 rows each)
// sequentially -> exactly 33 kv-tile-units per block (perfect balance).
// 4 waves = 4 q-heads of the kv group.  K double-buffered in LDS (padded),
// staged via regs with loads issued BEFORE the raw barrier (vmcnt never
// drained at barrier -> T14 async overlap).  V read directly global->VGPR
// fragments from V^T (L2-resident, 512KB/kv-head), issued early.
// Swapped QK^T (mfma(K,Q)) -> softmax reduce = 2 shfl_xor; P bounced through
// per-wave padded LDS into A-layout.  Exact defer-rescale skips O-rescale
// when the running max is unchanged.
// ---------------------------------------------------------------------------
__global__ __launch_bounds__(256, 2)
void attn_fwd(const unsigned short* __restrict__ Qm, const unsigned short* __restrict__ Km,
              const unsigned short* __restrict__ VTm, unsigned short* __restrict__ Om) {
  const int pair = blockIdx.x;  // 0..31
  const int kvh = blockIdx.y;   // NKV
  const int b = blockIdx.z;     // B
  const int tid = threadIdx.x;
  const int lane = tid & 63, w = tid >> 6;
  const int lr = lane & 15, lg = lane >> 4;
  const int h = kvh * 4 + w;

  __shared__ __align__(16) unsigned short Ksm[2][64 * 136];  // [key][d], pad +8
  __shared__ __align__(16) unsigned short Psm[4][32 * 72];   // per-wave [q][key], pad +8
  __shared__ __align__(16) float Alds[4][32];

  const float SCALE = 0.08838834764831845f;  // 1/sqrt(128)
  const float LOG2E = 1.4426950408889634f;

  const unsigned short* Kb0 = Km + ((size_t)(b * SLEN) * NKV + kvh) * HD;
  const unsigned short* VTb = VTm + ((size_t)(b * NKV + kvh) * HD) * SLEN;

#pragma unroll 1
  for (int halfq = 0; halfq < 2; ++halfq) {
    const int qt = halfq ? (63 - pair) : pair;
    const int q0 = qt * 32;
    const int ntiles = (q0 >> 6) + 1;

    // all waves done with Ksm from previous half before prologue re-writes it
    asm volatile("s_waitcnt lgkmcnt(0)" ::: "memory");
    __builtin_amdgcn_s_barrier();
    asm volatile("" ::: "memory");

    // hoist Q fragments: q = ni*16+lr, d = kd*32+lg*8
    bf16x8 qf[2][4];
    const unsigned short* Qb = Qm + ((size_t)(b * SLEN + q0) * NH + h) * HD;
#pragma unroll
    for (int ni = 0; ni < 2; ++ni)
#pragma unroll
      for (int kd = 0; kd < 4; ++kd)
        qf[ni][kd] = *(const bf16x8*)&Qb[(size_t)(ni * 16 + lr) * (NH * HD) + kd * 32 + lg * 8];

    f32x4 acc_o[2][8] = {};
    float m_run[2] = {-1e30f, -1e30f};
    float l_run[2] = {0.f, 0.f};

    // prologue: stage K tile 0 into Ksm[0]
    {
      bf16x8 k0[4];
#pragma unroll
      for (int i = 0; i < 4; ++i) {
        int c = tid + i * 256;
        k0[i] = *(const bf16x8*)&Kb0[(size_t)(c >> 4) * (NKV * HD) + (c & 15) * 8];
      }
#pragma unroll
      for (int i = 0; i < 4; ++i) {
        int c = tid + i * 256;
        *(bf16x8*)&Ksm[0][(c >> 4) * 136 + (c & 15) * 8] = k0[i];
      }
    }

#pragma unroll 1
    for (int t = 0; t < ntiles; ++t) {
      const int kv0 = t * 64;
      const unsigned short* Kcur = Ksm[t & 1];
      const bool more = (t + 1 < ntiles);

      // (1) V fragments for THIS tile: direct global->reg, issued early
      bf16x8 vf[2][8];
#pragma unroll
      for (int ks = 0; ks < 2; ++ks)
#pragma unroll
        for (int nd = 0; nd < 8; ++nd)
          vf[ks][nd] =
              *(const bf16x8*)&VTb[(size_t)(nd * 16 + lr) * SLEN + kv0 + ks * 32 + lg * 8];

      // (2) NEXT K tile -> regs, issued early (consumed at (8))
      bf16x8 knext[4];
      if (more) {
#pragma unroll
        for (int i = 0; i < 4; ++i) {
          int c = tid + i * 256;
          knext[i] =
              *(const bf16x8*)&Kb0[(size_t)(kv0 + 64 + (c >> 4)) * (NKV * HD) + (c & 15) * 8];
        }
      }

      // (3) raw barrier: LDS drained (lgkmcnt), global loads stay in flight
      asm volatile("s_waitcnt lgkmcnt(0)" ::: "memory");
      __builtin_amdgcn_s_barrier();
      asm volatile("" ::: "memory");

      // (4) S^T(64 key x 32 q) = K @ Q^T
      f32x4 accs[4][2] = {};
#pragma unroll
      for (int kd = 0; kd < 4; ++kd) {
        bf16x8 kf[4];
#pragma unroll
        for (int mi = 0; mi < 4; ++mi)
          kf[mi] = *(const bf16x8*)&Kcur[(mi * 16 + lr) * 136 + kd * 32 + lg * 8];
        __builtin_amdgcn_s_setprio(1);
#pragma unroll
        for (int mi = 0; mi < 4; ++mi)
#pragma unroll
          for (int ni = 0; ni < 2; ++ni)
            accs[mi][ni] =
                __builtin_amdgcn_mfma_f32_16x16x32_bf16(kf[mi], qf[ni][kd], accs[mi][ni], 0, 0, 0);
        __builtin_amdgcn_s_setprio(0);
      }

      // (5) online softmax
      const bool domask = (t == ntiles - 1);
      float alpha[2];
#pragma unroll
      for (int ni = 0; ni < 2; ++ni) {
        float cmax = -1e30f;
#pragma unroll
        for (int mi = 0; mi < 4; ++mi)
#pragma unroll
          for (int r = 0; r < 4; ++r) {
            float s = accs[mi][ni][r] * SCALE;
            if (domask) {
              int key = kv0 + mi * 16 + lg * 4 + r;
              int qq = q0 + ni * 16 + lr;
              if (key > qq) s = -1e30f;
            }
            accs[mi][ni][r] = s;
            cmax = fmaxf(cmax, s);
          }
        cmax = fmaxf(cmax, __shfl_xor(cmax, 16));
        cmax = fmaxf(cmax, __shfl_xor(cmax, 32));
        float mnew = fmaxf(m_run[ni], cmax);
        alpha[ni] = exp2f((m_run[ni] - mnew) * LOG2E);
        float psum = 0.f;
#pragma unroll
        for (int mi = 0; mi < 4; ++mi)
#pragma unroll
          for (int r = 0; r < 4; ++r) {
            float p = exp2f((accs[mi][ni][r] - mnew) * LOG2E);
            accs[mi][ni][r] = p;
            psum += p;
          }
        psum += __shfl_xor(psum, 16);
        psum += __shfl_xor(psum, 32);
        l_run[ni] = l_run[ni] * alpha[ni] + psum;
        m_run[ni] = mnew;
      }

      // exact defer-rescale: skip O-rescale when max unchanged (alpha==1)
      if (__any(alpha[0] < 1.f) || __any(alpha[1] < 1.f)) {
        if (lg == 0) { Alds[w][lr] = alpha[0]; Alds[w][16 + lr] = alpha[1]; }
        f32x4 al0 = *(const f32x4*)&Alds[w][lg * 4];
        f32x4 al1 = *(const f32x4*)&Alds[w][16 + lg * 4];
#pragma unroll
        for (int nd = 0; nd < 8; ++nd)
#pragma unroll
          for (int r = 0; r < 4; ++r) {
            acc_o[0][nd][r] *= al0[r];
            acc_o[1][nd][r] *= al1[r];
          }
      }

      // (6) P (S^T: row=key, col=q) -> Psm[q][key] bf16
#pragma unroll
      for (int ni = 0; ni < 2; ++ni)
#pragma unroll
        for (int mi = 0; mi < 4; ++mi)
#pragma unroll
          for (int rp = 0; rp < 4; rp += 2) {
            uint32_t pk = (uint32_t)f2bf(accs[mi][ni][rp]) |
                          ((uint32_t)f2bf(accs[mi][ni][rp + 1]) << 16);
            *(uint32_t*)&Psm[w][(ni * 16 + lr) * 72 + mi * 16 + lg * 4 + rp] = pk;
          }

      // (7) PV: O(32q x 128d) += P(32x64) @ V(64x128), V from early vf regs
#pragma unroll
      for (int ks = 0; ks < 2; ++ks) {
        bf16x8 pa[2];
#pragma unroll
        for (int pm = 0; pm < 2; ++pm)
          pa[pm] = *(const bf16x8*)&Psm[w][(pm * 16 + lr) * 72 + ks * 32 + lg * 8];
        __builtin_amdgcn_s_setprio(1);
#pragma unroll
        for (int nd = 0; nd < 8; ++nd)
#pragma unroll
          for (int pm = 0; pm < 2; ++pm)
            acc_o[pm][nd] =
                __builtin_amdgcn_mfma_f32_16x16x32_bf16(pa[pm], vf[ks][nd], acc_o[pm][nd], 0, 0, 0);
        __builtin_amdgcn_s_setprio(0);
      }

      // (8) write next K tile into the other LDS buffer
      if (more) {
#pragma unroll
        for (int i = 0; i < 4; ++i) {
          int c = tid + i * 256;
          *(bf16x8*)&Ksm[(t + 1) & 1][(c >> 4) * 136 + (c & 15) * 8] = knext[i];
        }
      }
    }

    // epilogue: O /= l, store bf16 at (b, q, h, d)
    if (lg == 0) {
      Alds[w][lr] = 1.f / l_run[0];
      Alds[w][16 + lr] = 1.f / l_run[1];
    }
    f32x4 li0 = *(const f32x4*)&Alds[w][lg * 4];
    f32x4 li1 = *(const f32x4*)&Alds[w][16 + lg * 4];
    unsigned short* Ob = Om + ((size_t)(b * SLEN + q0) * NH + h) * HD;
#pragma unroll
    for (int pm = 0; pm < 2; ++pm)
#pragma unroll
      for (int nd = 0; nd < 8; ++nd)
#pragma unroll
        for (int r = 0; r < 4; ++r) {
          int qq = pm * 16 + lg * 4 + r;
          float v = acc_o[pm][nd][r] * (pm ? li1[r] : li0[r]);
          Ob[(size_t)qq * (NH * HD) + nd * 16 + lr] = f2bf(v);
        }
  }
}

// ---------------------------------------------------------------------------
// Launcher.  d_in: hidden, attention_mask(unused: known causal), wq, wk, wv, wo
// ---------------------------------------------------------------------------
extern "C" void kernel_launch(void* const* d_in, const int* in_sizes, int n_in,
                              void* d_out, int out_size, void* d_ws, size_t ws_size,
                              hipStream_t stream) {
  const float* hidden = (const float*)d_in[0];
  const float* wq = (const float*)d_in[2];
  const float* wk = (const float*)d_in[3];
  const float* wv = (const float*)d_in[4];
  const float* wo = (const float*)d_in[5];

  char* ws = (char*)d_ws;
  unsigned short* Xbf = (unsigned short*)(ws + 0);          // 32 MB (B*S,4096)
  unsigned short* Qb  = (unsigned short*)(ws + 33554432);   // 32 MB (B*S,4096)
  unsigned short* Ob  = (unsigned short*)(ws + 67108864);   // 32 MB (B*S,4096)
  unsigned short* Wb  = (unsigned short*)(ws + 100663296);  // 32 MB wq, later wo
  unsigned short* Kb  = (unsigned short*)(ws + 134217728);  // 8 MB (B*S,1024)
  unsigned short* Vb  = (unsigned short*)(ws + 142606336);  // 8 MB (B*S,1024)
  unsigned short* VTb = (unsigned short*)(ws + 150994944);  // 8 MB (B,8,128,S)
  unsigned short* Wkb = (unsigned short*)(ws + 159383552);  // 8 MB
  unsigned short* Wvb = (unsigned short*)(ws + 167772160);  // 8 MB
  float* ct = (float*)(ws + 176160768);                     // 0.5 MB
  float* st = (float*)(ws + 176685056);                     // 0.5 MB

  // 1) bf16 casts
  cvt_f32_bf16<<<8192, 256, 0, stream>>>(hidden, Xbf);
  cvt_f32_bf16<<<8192, 256, 0, stream>>>(wq, Wb);
  cvt_f32_bf16<<<2048, 256, 0, stream>>>(wk, Wkb);
  cvt_f32_bf16<<<2048, 256, 0, stream>>>(wv, Wvb);

  // 2) projections
  gemm_bt<unsigned short><<<1024, 256, 0, stream>>>(Xbf, Wb, Qb, 4096, 4096, 4096);
  gemm_bt<unsigned short><<<256, 256, 0, stream>>>(Xbf, Wkb, Kb, 4096, 1024, 4096);
  gemm_bt<unsigned short><<<256, 256, 0, stream>>>(Xbf, Wvb, Vb, 4096, 1024, 4096);

  // 3) RoPE
  rope_tables<<<512, 256, 0, stream>>>(ct, st);
  rope_apply<<<4096, 256, 0, stream>>>(Qb, ct, st, NH);
  rope_apply<<<1024, 256, 0, stream>>>(Kb, ct, st, NKV);

  // 4) V -> V^T
  transpose_v<<<dim3(64, 16), 256, 0, stream>>>(Vb, VTb);

  // 5) causal GQA flash attention (paired q-tiles for load balance)
  attn_fwd<<<dim3(32, NKV, BATCH), 256, 0, stream>>>(Qb, Kb, VTb, Ob);

  // 6) output projection (fp32 out)
  cvt_f32_bf16<<<8192, 256, 0, stream>>>(wo, Wb);
  gemm_bt<float><<<1024, 256, 0, stream>>>(Ob, Wb, (float*)d_out, 4096, 4096, 4096);
}

// Round 3
// 650.568 us; speedup vs baseline: 1.2151x; 1.2151x over previous
//
#include <hip/hip_runtime.h>
#include <hip/hip_bf16.h>
#include <stdint.h>

// ---------------------------------------------------------------------------
// GroupedQueryAttention: hidden(B,S,4096) -> fused QKV proj -> RoPE -> causal
// GQA flash attention -> out proj.  B=2 S=2048 H=32 Hk=8 D=128.  bf16 MFMA.
// ---------------------------------------------------------------------------

#define HIDDEN 4096
#define NH 32
#define NKV 8
#define HD 128
#define SLEN 2048
#define BATCH 2
#define QKVLD 6144  // fused QKV row stride (cols: Q 0..4095, K 4096..5119, V 5120..6143)

typedef __attribute__((ext_vector_type(8))) short bf16x8;
typedef __attribute__((ext_vector_type(4))) float f32x4;

__device__ __forceinline__ unsigned short f2bf(float f) {
  __hip_bfloat16 h = __float2bfloat16(f);
  return *reinterpret_cast<unsigned short*>(&h);
}
__device__ __forceinline__ float bf2f(unsigned short h) {
  union { uint32_t u; float f; } v; v.u = ((uint32_t)h) << 16;
  return v.f;
}
__device__ __forceinline__ void gload_lds16(const void* g, void* l) {
  __builtin_amdgcn_global_load_lds(
      (const __attribute__((address_space(1))) unsigned int*)g,
      (__attribute__((address_space(3))) unsigned int*)l, 16, 0, 0);
}

// ---------------------------------------------------------------------------
// fp32 -> bf16 convert, 8 elems/thread. n = grid*2048 exactly.
// ---------------------------------------------------------------------------
__global__ __launch_bounds__(256) void cvt_f32_bf16(const float* __restrict__ in,
                                                    unsigned short* __restrict__ out) {
  size_t i = ((size_t)blockIdx.x * 256 + threadIdx.x) * 8;
  f32x4 a = *(const f32x4*)&in[i];
  f32x4 b = *(const f32x4*)&in[i + 4];
  bf16x8 o;
#pragma unroll
  for (int j = 0; j < 4; ++j) { o[j] = (short)f2bf(a[j]); o[4 + j] = (short)f2bf(b[j]); }
  *(bf16x8*)&out[i] = o;
}

// ---------------------------------------------------------------------------
// GEMM  C(M,N) = A(M,K) @ B(N,K)^T, bf16 in, OutT out.  m97 structure:
// 128x128 tile, BK=32, 4 waves, global_load_lds w=16, XCD swizzle.
// ---------------------------------------------------------------------------
__device__ __forceinline__ void store_out(unsigned short* C, size_t i, float v) { C[i] = f2bf(v); }
__device__ __forceinline__ void store_out(float* C, size_t i, float v) { C[i] = v; }

template <typename OutT>
__global__ __launch_bounds__(256, 2)
void gemm_bt(const unsigned short* __restrict__ A, const unsigned short* __restrict__ B,
             OutT* __restrict__ C, int M, int N, int K) {
  __shared__ __align__(16) unsigned short Asm[128 * 32];
  __shared__ __align__(16) unsigned short Bsm[128 * 32];
  const int tid = threadIdx.x;
  const int lane = tid & 63, wid = tid >> 6;
  const int lr = lane & 15, lg = lane >> 4;
  const int wr = wid >> 1, wc = wid & 1;

  const int nbn = N >> 7;
  const int nwg = gridDim.x;
  int wg = (int)blockIdx.x;
  wg = (wg & 7) * (nwg >> 3) + (wg >> 3);  // XCD-aware swizzle (nwg%8==0)
  const int bm = wg / nbn, bn = wg % nbn;

  const unsigned short* Ab = A + (size_t)bm * 128 * K;
  const unsigned short* Bb = B + (size_t)bn * 128 * K;

  f32x4 acc[4][4] = {};

  const int c0 = tid, c1 = tid + 256;
  const int ar0 = c0 >> 2, ak0 = (c0 & 3) * 8;
  const int ar1 = c1 >> 2, ak1 = (c1 & 3) * 8;

  for (int kt = 0; kt < K; kt += 32) {
    __syncthreads();
    gload_lds16(Ab + (size_t)ar0 * K + kt + ak0, &Asm[c0 * 8]);
    gload_lds16(Ab + (size_t)ar1 * K + kt + ak1, &Asm[c1 * 8]);
    gload_lds16(Bb + (size_t)ar0 * K + kt + ak0, &Bsm[c0 * 8]);
    gload_lds16(Bb + (size_t)ar1 * K + kt + ak1, &Bsm[c1 * 8]);
    __syncthreads();

    bf16x8 af[4], bfr[4];
#pragma unroll
    for (int mi = 0; mi < 4; ++mi)
      af[mi] = *(const bf16x8*)&Asm[(wr * 64 + mi * 16 + lr) * 32 + lg * 8];
#pragma unroll
    for (int ni = 0; ni < 4; ++ni)
      bfr[ni] = *(const bf16x8*)&Bsm[(wc * 64 + ni * 16 + lr) * 32 + lg * 8];
#pragma unroll
    for (int mi = 0; mi < 4; ++mi)
#pragma unroll
      for (int ni = 0; ni < 4; ++ni)
        acc[mi][ni] = __builtin_amdgcn_mfma_f32_16x16x32_bf16(af[mi], bfr[ni], acc[mi][ni], 0, 0, 0);
  }

#pragma unroll
  for (int mi = 0; mi < 4; ++mi)
#pragma unroll
    for (int ni = 0; ni < 4; ++ni)
#pragma unroll
      for (int r = 0; r < 4; ++r) {
        size_t row = (size_t)bm * 128 + wr * 64 + mi * 16 + lg * 4 + r;
        size_t col = (size_t)bn * 128 + wc * 64 + ni * 16 + lr;
        store_out(C, row * N + col, acc[mi][ni][r]);
      }
}

// ---------------------------------------------------------------------------
// RoPE tables + apply (row stride / base-offset parametrized for fused QKV)
// ---------------------------------------------------------------------------
__global__ __launch_bounds__(256) void rope_tables(float* __restrict__ ct, float* __restrict__ st) {
  int idx = blockIdx.x * 256 + threadIdx.x;  // S*64
  int s = idx >> 6, j = idx & 63;
  float inv = exp2f(-(float)j * (13.287712379549449f / 64.f));
  float f = (float)s * inv;
  ct[idx] = cosf(f);
  st[idx] = sinf(f);
}

__global__ __launch_bounds__(256) void rope_apply(unsigned short* __restrict__ X, int ld,
                                                  const float* __restrict__ ct,
                                                  const float* __restrict__ st, int heads) {
  int idx = blockIdx.x * 256 + threadIdx.x;
  int jc = (idx & 7) * 8;
  int t2 = idx >> 3;
  int hh = t2 % heads;
  int row = t2 / heads;
  int s = row & (SLEN - 1);
  unsigned short* p = X + (size_t)row * ld + hh * HD;
  bf16x8 lo = *(bf16x8*)&p[jc];
  bf16x8 hi = *(bf16x8*)&p[64 + jc];
  bf16x8 nlo, nhi;
#pragma unroll
  for (int j = 0; j < 8; ++j) {
    float c = ct[s * 64 + jc + j];
    float sn = st[s * 64 + jc + j];
    float xl = bf2f((unsigned short)(lo[j]));
    float xh = bf2f((unsigned short)(hi[j]));
    nlo[j] = (short)f2bf(xl * c - xh * sn);
    nhi[j] = (short)f2bf(xh * c + xl * sn);
  }
  *(bf16x8*)&p[jc] = nlo;
  *(bf16x8*)&p[64 + jc] = nhi;
}

// ---------------------------------------------------------------------------
// V (rows B*S at stride ld, 1024 cols) -> VT (B, NKV, HD, S)
// ---------------------------------------------------------------------------
__global__ __launch_bounds__(256) void transpose_v(const unsigned short* __restrict__ Vsrc, int ld,
                                                   unsigned short* __restrict__ VT) {
  __shared__ unsigned short tile[64][66];
  const int t = threadIdx.x;
  const int bs = blockIdx.x;
  const int bd = blockIdx.y;
  const int b = bs >> 5;
  const int s0 = (bs & 31) * 64;
  const int d0 = bd * 64;
#pragma unroll
  for (int it = 0; it < 2; ++it) {
    int si = (t >> 3) + it * 32;
    int dj = (t & 7) * 8;
    bf16x8 v = *(const bf16x8*)&Vsrc[(size_t)(b * SLEN + s0 + si) * ld + d0 + dj];
#pragma unroll
    for (int j = 0; j < 8; ++j) tile[si][dj + j] = (unsigned short)(v[j]);
  }
  __syncthreads();
#pragma unroll
  for (int it = 0; it < 2; ++it) {
    int di = (t >> 3) + it * 32;
    int sj = (t & 7) * 8;
    bf16x8 o;
#pragma unroll
    for (int j = 0; j < 8; ++j) o[j] = (short)tile[sj + j][di];
    int c = d0 + di;
    int kvh = c >> 7, d = c & 127;
    *(bf16x8*)&VT[(((size_t)b * NKV + kvh) * HD + d) * SLEN + s0 + sj] = o;
  }
}

// ---------------------------------------------------------------------------
// Flash attention v3.
// Grid 512 blocks, decoded so all 32 pair-blocks of a (b,kvh) group land on
// ONE XCD (K+V of 2 groups = 2 MB -> L2-resident).  Block = 4 waves = 4 heads;
// each block does q-tiles {pair, 63-pair} (exactly 33 kv-tile-units, balanced).
// K [64][136] and V^T [128][72] single-buffered in LDS (padded, ~conflict-free),
// T14 staging: next tile global->reg prefetch issued right after LDS publish,
// consumed at next iteration's __syncthreads (its vmcnt(0) is the wait we need)
// -> HBM/L2 latency hidden under full tile compute, no spills.
// Swapped QK^T (mfma(K,Q)); softmax in log2*scale domain; exact defer-rescale.
// ---------------------------------------------------------------------------
__global__ __launch_bounds__(256, 2)
void attn_fwd(const unsigned short* __restrict__ QKV, const unsigned short* __restrict__ VTm,
              unsigned short* __restrict__ Om) {
  const int blk = blockIdx.x;            // 0..511
  const int xcd = blk & 7, jj = blk >> 3;
  const int g = xcd + ((jj >> 5) << 3);  // (b,kvh) group 0..15, pinned per XCD
  const int pair = jj & 31;
  const int kvh = g & 7, b = g >> 3;
  const int tid = threadIdx.x;
  const int lane = tid & 63, w = tid >> 6;
  const int lr = lane & 15, lg = lane >> 4;
  const int h = kvh * 4 + w;

  __shared__ __align__(16) unsigned short Ksm[64 * 136];   // [key][d], pad +8
  __shared__ __align__(16) unsigned short Vsm[128 * 72];   // [d][key], pad +8
  __shared__ __align__(16) unsigned short Psm[4][32 * 72]; // per-wave [q][key], pad +8
  __shared__ float Alds[4][32];

  const float SL2E = 0.1275378504229740f;  // (1/sqrt(128)) * log2(e)

  const unsigned short* Kb0 = QKV + (size_t)(b * SLEN) * QKVLD + 4096 + kvh * HD;
  const unsigned short* VTb = VTm + ((size_t)(b * NKV + kvh) * HD) * SLEN;

#pragma unroll 1
  for (int halfq = 0; halfq < 2; ++halfq) {
    const int qt = halfq ? (63 - pair) : pair;
    const int q0 = qt * 32;
    const int ntiles = (qt >> 1) + 1;

    // Q fragments: q = ni*16+lr, d = kd*32+lg*8
    bf16x8 qf[2][4];
    const unsigned short* Qb = QKV + (size_t)(b * SLEN + q0) * QKVLD + h * HD;
#pragma unroll
    for (int ni = 0; ni < 2; ++ni)
#pragma unroll
      for (int kd = 0; kd < 4; ++kd)
        qf[ni][kd] = *(const bf16x8*)&Qb[(size_t)(ni * 16 + lr) * QKVLD + kd * 32 + lg * 8];

    f32x4 acc_o[2][8] = {};
    float m_run[2] = {-1e30f, -1e30f};
    float l_run[2] = {0.f, 0.f};

    // prefetch tile 0 -> regs (16+16 VGPRs, consumed at first barrier)
    bf16x8 kreg[4], vreg[4];
#pragma unroll
    for (int i = 0; i < 4; ++i) {
      int c = tid + i * 256;
      kreg[i] = *(const bf16x8*)&Kb0[(size_t)(c >> 4) * QKVLD + (c & 15) * 8];
      vreg[i] = *(const bf16x8*)&VTb[(size_t)(c >> 3) * SLEN + (c & 7) * 8];
    }

#pragma unroll 1
    for (int t = 0; t < ntiles; ++t) {
      const int kv0 = t * 64;
      // A: waits vmcnt(0) (kreg/vreg arrived) + all waves done reading prev tile
      __syncthreads();
#pragma unroll
      for (int i = 0; i < 4; ++i) {
        int c = tid + i * 256;
        *(bf16x8*)&Ksm[(c >> 4) * 136 + (c & 15) * 8] = kreg[i];
        *(bf16x8*)&Vsm[(c >> 3) * 72 + (c & 7) * 8] = vreg[i];
      }
      __syncthreads();  // B: tile visible to all waves

      // T14: issue NEXT tile loads now; in flight across the whole compute
      if (t + 1 < ntiles) {
#pragma unroll
        for (int i = 0; i < 4; ++i) {
          int c = tid + i * 256;
          kreg[i] = *(const bf16x8*)&Kb0[(size_t)(kv0 + 64 + (c >> 4)) * QKVLD + (c & 15) * 8];
          vreg[i] = *(const bf16x8*)&VTb[(size_t)(c >> 3) * SLEN + kv0 + 64 + (c & 7) * 8];
        }
      }

      // QK^T: S^T(64 key x 32 q) = K @ Q^T
      f32x4 accs[4][2] = {};
#pragma unroll
      for (int kd = 0; kd < 4; ++kd) {
        bf16x8 kf[4];
#pragma unroll
        for (int mi = 0; mi < 4; ++mi)
          kf[mi] = *(const bf16x8*)&Ksm[(mi * 16 + lr) * 136 + kd * 32 + lg * 8];
        __builtin_amdgcn_s_setprio(1);
#pragma unroll
        for (int mi = 0; mi < 4; ++mi)
#pragma unroll
          for (int ni = 0; ni < 2; ++ni)
            accs[mi][ni] =
                __builtin_amdgcn_mfma_f32_16x16x32_bf16(kf[mi], qf[ni][kd], accs[mi][ni], 0, 0, 0);
        __builtin_amdgcn_s_setprio(0);
      }

      // online softmax, log2*scale domain
      const bool domask = (t == ntiles - 1);
      float alpha[2];
#pragma unroll
      for (int ni = 0; ni < 2; ++ni) {
        float cmax = -1e30f;
#pragma unroll
        for (int mi = 0; mi < 4; ++mi)
#pragma unroll
          for (int r = 0; r < 4; ++r) {
            float s = accs[mi][ni][r] * SL2E;
            if (domask) {
              int key = kv0 + mi * 16 + lg * 4 + r;
              int qq = q0 + ni * 16 + lr;
              if (key > qq) s = -1e30f;
            }
            accs[mi][ni][r] = s;
            cmax = fmaxf(cmax, s);
          }
        cmax = fmaxf(cmax, __shfl_xor(cmax, 16));
        cmax = fmaxf(cmax, __shfl_xor(cmax, 32));
        float mnew = fmaxf(m_run[ni], cmax);
        alpha[ni] = exp2f(m_run[ni] - mnew);
        float psum = 0.f;
#pragma unroll
        for (int mi = 0; mi < 4; ++mi)
#pragma unroll
          for (int r = 0; r < 4; ++r) {
            float p = exp2f(accs[mi][ni][r] - mnew);
            accs[mi][ni][r] = p;
            psum += p;
          }
        psum += __shfl_xor(psum, 16);
        psum += __shfl_xor(psum, 32);
        l_run[ni] = l_run[ni] * alpha[ni] + psum;
        m_run[ni] = mnew;
      }

      // exact defer-rescale: skip when running max unchanged (alpha==1)
      if (__any(alpha[0] < 1.f) || __any(alpha[1] < 1.f)) {
        if (lg == 0) { Alds[w][lr] = alpha[0]; Alds[w][16 + lr] = alpha[1]; }
        f32x4 al0 = *(const f32x4*)&Alds[w][lg * 4];
        f32x4 al1 = *(const f32x4*)&Alds[w][16 + lg * 4];
#pragma unroll
        for (int nd = 0; nd < 8; ++nd)
#pragma unroll
          for (int r = 0; r < 4; ++r) {
            acc_o[0][nd][r] *= al0[r];
            acc_o[1][nd][r] *= al1[r];
          }
      }

      // P (S^T: row=key, col=q) -> Psm[q][key] bf16
#pragma unroll
      for (int ni = 0; ni < 2; ++ni)
#pragma unroll
        for (int mi = 0; mi < 4; ++mi)
#pragma unroll
          for (int rp = 0; rp < 4; rp += 2) {
            uint32_t pk = (uint32_t)f2bf(accs[mi][ni][rp]) |
                          ((uint32_t)f2bf(accs[mi][ni][rp + 1]) << 16);
            *(uint32_t*)&Psm[w][(ni * 16 + lr) * 72 + mi * 16 + lg * 4 + rp] = pk;
          }

      // PV: O(32q x 128d) += P(32x64) @ V(64x128)
#pragma unroll
      for (int ks = 0; ks < 2; ++ks) {
        bf16x8 pa[2];
#pragma unroll
        for (int pm = 0; pm < 2; ++pm)
          pa[pm] = *(const bf16x8*)&Psm[w][(pm * 16 + lr) * 72 + ks * 32 + lg * 8];
        __builtin_amdgcn_s_setprio(1);
#pragma unroll
        for (int nd = 0; nd < 8; ++nd) {
          bf16x8 vb = *(const bf16x8*)&Vsm[(nd * 16 + lr) * 72 + ks * 32 + lg * 8];
#pragma unroll
          for (int pm = 0; pm < 2; ++pm)
            acc_o[pm][nd] =
                __builtin_amdgcn_mfma_f32_16x16x32_bf16(pa[pm], vb, acc_o[pm][nd], 0, 0, 0);
        }
        __builtin_amdgcn_s_setprio(0);
      }
    }

    // epilogue: O /= l, store bf16 at (b, q, h, d)
    if (lg == 0) {
      Alds[w][lr] = 1.f / l_run[0];
      Alds[w][16 + lr] = 1.f / l_run[1];
    }
    f32x4 li0 = *(const f32x4*)&Alds[w][lg * 4];
    f32x4 li1 = *(const f32x4*)&Alds[w][16 + lg * 4];
    unsigned short* Ob = Om + ((size_t)(b * SLEN + q0) * NH + h) * HD;
#pragma unroll
    for (int pm = 0; pm < 2; ++pm)
#pragma unroll
      for (int nd = 0; nd < 8; ++nd)
#pragma unroll
        for (int r = 0; r < 4; ++r) {
          int qq = pm * 16 + lg * 4 + r;
          float v = acc_o[pm][nd][r] * (pm ? li1[r] : li0[r]);
          Ob[(size_t)qq * (NH * HD) + nd * 16 + lr] = f2bf(v);
        }
  }
}

// ---------------------------------------------------------------------------
// Launcher.  d_in: hidden, attention_mask(unused: known causal), wq, wk, wv, wo
// Workspace (169 MB): Xbf 32 | Wqkv 48 | QKV 48 | Ob 32 | VTb 8 | ct/st 1
// ---------------------------------------------------------------------------
extern "C" void kernel_launch(void* const* d_in, const int* in_sizes, int n_in,
                              void* d_out, int out_size, void* d_ws, size_t ws_size,
                              hipStream_t stream) {
  const float* hidden = (const float*)d_in[0];
  const float* wq = (const float*)d_in[2];
  const float* wk = (const float*)d_in[3];
  const float* wv = (const float*)d_in[4];
  const float* wo = (const float*)d_in[5];

  char* ws = (char*)d_ws;
  const size_t MB = 1ull << 20;
  unsigned short* Xbf  = (unsigned short*)(ws);             // 32 MB (B*S,4096)
  unsigned short* Wqkv = (unsigned short*)(ws + 32 * MB);   // 48 MB (6144,4096) packed W
  unsigned short* QKV  = (unsigned short*)(ws + 80 * MB);   // 48 MB (B*S,6144)
  unsigned short* Ob   = (unsigned short*)(ws + 128 * MB);  // 32 MB (B*S,4096)
  unsigned short* VTb  = (unsigned short*)(ws + 160 * MB);  // 8 MB (B,8,128,S)
  float* ct = (float*)(ws + 168 * MB);                      // 0.5 MB
  float* st = (float*)(ws + 168 * MB + 524288);             // 0.5 MB

  // 1) bf16 casts (weights packed: Wq rows 0..4095, Wk 4096..5119, Wv 5120..6143)
  cvt_f32_bf16<<<8192, 256, 0, stream>>>(hidden, Xbf);
  cvt_f32_bf16<<<8192, 256, 0, stream>>>(wq, Wqkv);
  cvt_f32_bf16<<<2048, 256, 0, stream>>>(wk, Wqkv + (size_t)4096 * 4096);
  cvt_f32_bf16<<<2048, 256, 0, stream>>>(wv, Wqkv + (size_t)5120 * 4096);

  // 2) fused QKV projection: (4096,4096) @ (6144,4096)^T -> (4096,6144)
  gemm_bt<unsigned short><<<1536, 256, 0, stream>>>(Xbf, Wqkv, QKV, 4096, 6144, 4096);

  // 3) RoPE on Q and K columns of fused buffer
  rope_tables<<<512, 256, 0, stream>>>(ct, st);
  rope_apply<<<4096, 256, 0, stream>>>(QKV, QKVLD, ct, st, NH);
  rope_apply<<<1024, 256, 0, stream>>>(QKV + 4096, QKVLD, ct, st, NKV);

  // 4) V -> V^T
  transpose_v<<<dim3(64, 16), 256, 0, stream>>>(QKV + 5120, QKVLD, VTb);

  // 5) causal GQA flash attention (paired q-tiles, XCD-grouped)
  attn_fwd<<<512, 256, 0, stream>>>(QKV, VTb, Ob);

  // 6) output projection (fp32 out); Wqkv region reused for Wo
  cvt_f32_bf16<<<8192, 256, 0, stream>>>(wo, Wqkv);
  gemm_bt<float><<<1024, 256, 0, stream>>>(Ob, Wqkv, (float*)d_out, 4096, 4096, 4096);
}

// Round 4
// 601.098 us; speedup vs baseline: 1.3151x; 1.0823x over previous
//
#include <hip/hip_runtime.h>
#include <hip/hip_bf16.h>
#include <stdint.h>

// ---------------------------------------------------------------------------
// GroupedQueryAttention: hidden(B,S,4096) -> fused QKV proj -> RoPE -> causal
// GQA flash attention -> out proj.  B=2 S=2048 H=32 Hk=8 D=128.  bf16 MFMA.
// ---------------------------------------------------------------------------

#define HIDDEN 4096
#define NH 32
#define NKV 8
#define HD 128
#define SLEN 2048
#define BATCH 2
#define QKVLD 6144  // fused QKV row stride (cols: Q 0..4095, K 4096..5119, V 5120..6143)

typedef __attribute__((ext_vector_type(8))) short bf16x8;
typedef __attribute__((ext_vector_type(4))) float f32x4;

__device__ __forceinline__ unsigned short f2bf(float f) {
  __hip_bfloat16 h = __float2bfloat16(f);
  return *reinterpret_cast<unsigned short*>(&h);
}
__device__ __forceinline__ float bf2f(unsigned short h) {
  union { uint32_t u; float f; } v; v.u = ((uint32_t)h) << 16;
  return v.f;
}
__device__ __forceinline__ void gload_lds16(const void* g, void* l) {
  __builtin_amdgcn_global_load_lds(
      (const __attribute__((address_space(1))) unsigned int*)g,
      (__attribute__((address_space(3))) unsigned int*)l, 16, 0, 0);
}

// ---------------------------------------------------------------------------
// fp32 -> bf16 convert, 8 elems/thread. n = grid*2048 exactly.
// ---------------------------------------------------------------------------
__global__ __launch_bounds__(256) void cvt_f32_bf16(const float* __restrict__ in,
                                                    unsigned short* __restrict__ out) {
  size_t i = ((size_t)blockIdx.x * 256 + threadIdx.x) * 8;
  f32x4 a = *(const f32x4*)&in[i];
  f32x4 b = *(const f32x4*)&in[i + 4];
  bf16x8 o;
#pragma unroll
  for (int j = 0; j < 4; ++j) { o[j] = (short)f2bf(a[j]); o[4 + j] = (short)f2bf(b[j]); }
  *(bf16x8*)&out[i] = o;
}

// ---------------------------------------------------------------------------
// GEMM  C(M,N) = A(M,K) @ B(N,K)^T, bf16 in, OutT out.
// 256x256 tile, BK=32, 8 waves (2x4 -> 128x64 each), 512 threads.
// 4-deep LDS pipeline (4 x 32KB K-tile buffers = 128 KiB):
//   iter t: issue stage(t+3) -> buf[(t+3)&3]; ds_read+MFMA tile t from
//   buf[t&3]; s_waitcnt vmcnt(8) (tile t+1 landed, t+2/t+3 stay in flight);
//   s_barrier.  Counted vmcnt (T4) -- never drained in steady state.
// Linear LDS [256][32] bf16: 64B rows put the wave's 64 b128 frag reads on
// all 8 bank-quads x8 (the b128 floor) -> conflict-balanced, no swizzle.
// M,N multiples of 256; K multiple of 32 (>=96); grid % 8 == 0.
// ---------------------------------------------------------------------------
__device__ __forceinline__ void store_out(unsigned short* C, size_t i, float v) { C[i] = f2bf(v); }
__device__ __forceinline__ void store_out(float* C, size_t i, float v) { C[i] = v; }

template <typename OutT>
__global__ __launch_bounds__(512, 2)
void gemm_bt256(const unsigned short* __restrict__ A, const unsigned short* __restrict__ B,
                OutT* __restrict__ C, int M, int N, int K) {
  // 4 buffers x (A: 1024 chunks | B: 1024 chunks), chunk = 16B = 8 bf16
  __shared__ __align__(16) unsigned short lds[4 * 2048 * 8];

  const int tid = threadIdx.x;
  const int lane = tid & 63, w = tid >> 6;
  const int lr = lane & 15, lg = lane >> 4;
  const int wr = w >> 2, wc = w & 3;  // 2 x 4 wave grid

  const int nbn = N >> 8;
  const int nwg = gridDim.x;
  int wg = (int)blockIdx.x;
  wg = (wg & 7) * (nwg >> 3) + (wg >> 3);  // XCD-aware swizzle (nwg%8==0)
  const int bm = wg / nbn, bn = wg % nbn;

  const unsigned short* Ab = A + (size_t)bm * 256 * K;
  const unsigned short* Bb = B + (size_t)bn * 256 * K;

  f32x4 acc[8][4] = {};

  // stage one K-tile (A 16KB + B 16KB) into buf[t&3]: 4 gload_lds16/thread
  auto stage = [&](int t2) {
    const int kt = t2 * 32;
    unsigned short* lb = lds + (size_t)(t2 & 3) * 2048 * 8;
#pragma unroll
    for (int j = 0; j < 2; ++j) {
      int idx = tid + j * 512;  // A chunk in [0,1024): row=idx>>2, colchunk=idx&3
      gload_lds16(Ab + (size_t)(idx >> 2) * K + kt + (idx & 3) * 8,
                  lb + (size_t)(w * 64 + j * 512) * 8);
    }
#pragma unroll
    for (int j = 0; j < 2; ++j) {
      int idx = tid + j * 512;
      gload_lds16(Bb + (size_t)(idx >> 2) * K + kt + (idx & 3) * 8,
                  lb + (size_t)(1024 + w * 64 + j * 512) * 8);
    }
  };

  const int NT = K >> 5;

  // prologue: fill 3 tiles ahead; wait tile 0 only (vmcnt(8): G1,G2 in flight)
  stage(0);
  stage(1);
  stage(2);
  asm volatile("s_waitcnt vmcnt(8)" ::: "memory");
  __builtin_amdgcn_s_barrier();
  asm volatile("" ::: "memory");

#pragma unroll 1
  for (int t = 0; t < NT; ++t) {
    if (t + 3 < NT) stage(t + 3);

    const unsigned short* bufp = lds + (size_t)(t & 3) * 2048 * 8;
    bf16x8 af[8], bfv[4];
#pragma unroll
    for (int mi = 0; mi < 8; ++mi)
      af[mi] = *(const bf16x8*)&bufp[(size_t)(wr * 512 + mi * 64 + lr * 4 + lg) * 8];
#pragma unroll
    for (int ni = 0; ni < 4; ++ni)
      bfv[ni] = *(const bf16x8*)&bufp[(size_t)(1024 + wc * 256 + ni * 64 + lr * 4 + lg) * 8];

    __builtin_amdgcn_s_setprio(1);
#pragma unroll
    for (int mi = 0; mi < 8; ++mi)
#pragma unroll
      for (int ni = 0; ni < 4; ++ni)
        acc[mi][ni] = __builtin_amdgcn_mfma_f32_16x16x32_bf16(af[mi], bfv[ni], acc[mi][ni], 0, 0, 0);
    __builtin_amdgcn_s_setprio(0);

    if (t + 1 < NT) {
      if (t + 3 < NT)      asm volatile("s_waitcnt vmcnt(8)" ::: "memory");
      else if (t + 2 < NT) asm volatile("s_waitcnt vmcnt(4)" ::: "memory");
      else                 asm volatile("s_waitcnt vmcnt(0)" ::: "memory");
      __builtin_amdgcn_s_barrier();
      asm volatile("" ::: "memory");
    }
  }

#pragma unroll
  for (int mi = 0; mi < 8; ++mi)
#pragma unroll
    for (int ni = 0; ni < 4; ++ni)
#pragma unroll
      for (int r = 0; r < 4; ++r) {
        size_t row = (size_t)bm * 256 + wr * 128 + mi * 16 + lg * 4 + r;
        size_t col = (size_t)bn * 256 + wc * 64 + ni * 16 + lr;
        store_out(C, row * N + col, acc[mi][ni][r]);
      }
}

// ---------------------------------------------------------------------------
// RoPE tables + apply
// ---------------------------------------------------------------------------
__global__ __launch_bounds__(256) void rope_tables(float* __restrict__ ct, float* __restrict__ st) {
  int idx = blockIdx.x * 256 + threadIdx.x;  // S*64
  int s = idx >> 6, j = idx & 63;
  float inv = exp2f(-(float)j * (13.287712379549449f / 64.f));
  float f = (float)s * inv;
  ct[idx] = cosf(f);
  st[idx] = sinf(f);
}

__global__ __launch_bounds__(256) void rope_apply(unsigned short* __restrict__ X, int ld,
                                                  const float* __restrict__ ct,
                                                  const float* __restrict__ st, int heads) {
  int idx = blockIdx.x * 256 + threadIdx.x;
  int jc = (idx & 7) * 8;
  int t2 = idx >> 3;
  int hh = t2 % heads;
  int row = t2 / heads;
  int s = row & (SLEN - 1);
  unsigned short* p = X + (size_t)row * ld + hh * HD;
  bf16x8 lo = *(bf16x8*)&p[jc];
  bf16x8 hi = *(bf16x8*)&p[64 + jc];
  bf16x8 nlo, nhi;
#pragma unroll
  for (int j = 0; j < 8; ++j) {
    float c = ct[s * 64 + jc + j];
    float sn = st[s * 64 + jc + j];
    float xl = bf2f((unsigned short)(lo[j]));
    float xh = bf2f((unsigned short)(hi[j]));
    nlo[j] = (short)f2bf(xl * c - xh * sn);
    nhi[j] = (short)f2bf(xh * c + xl * sn);
  }
  *(bf16x8*)&p[jc] = nlo;
  *(bf16x8*)&p[64 + jc] = nhi;
}

// ---------------------------------------------------------------------------
// V (rows B*S at stride ld, 1024 cols) -> VT (B, NKV, HD, S)
// ---------------------------------------------------------------------------
__global__ __launch_bounds__(256) void transpose_v(const unsigned short* __restrict__ Vsrc, int ld,
                                                   unsigned short* __restrict__ VT) {
  __shared__ unsigned short tile[64][66];
  const int t = threadIdx.x;
  const int bs = blockIdx.x;
  const int bd = blockIdx.y;
  const int b = bs >> 5;
  const int s0 = (bs & 31) * 64;
  const int d0 = bd * 64;
#pragma unroll
  for (int it = 0; it < 2; ++it) {
    int si = (t >> 3) + it * 32;
    int dj = (t & 7) * 8;
    bf16x8 v = *(const bf16x8*)&Vsrc[(size_t)(b * SLEN + s0 + si) * ld + d0 + dj];
#pragma unroll
    for (int j = 0; j < 8; ++j) tile[si][dj + j] = (unsigned short)(v[j]);
  }
  __syncthreads();
#pragma unroll
  for (int it = 0; it < 2; ++it) {
    int di = (t >> 3) + it * 32;
    int sj = (t & 7) * 8;
    bf16x8 o;
#pragma unroll
    for (int j = 0; j < 8; ++j) o[j] = (short)tile[sj + j][di];
    int c = d0 + di;
    int kvh = c >> 7, d = c & 127;
    *(bf16x8*)&VT[(((size_t)b * NKV + kvh) * HD + d) * SLEN + s0 + sj] = o;
  }
}

// ---------------------------------------------------------------------------
// Flash attention (round-3 version, validated).
// ---------------------------------------------------------------------------
__global__ __launch_bounds__(256, 2)
void attn_fwd(const unsigned short* __restrict__ QKV, const unsigned short* __restrict__ VTm,
              unsigned short* __restrict__ Om) {
  const int blk = blockIdx.x;            // 0..511
  const int xcd = blk & 7, jj = blk >> 3;
  const int g = xcd + ((jj >> 5) << 3);  // (b,kvh) group 0..15, pinned per XCD
  const int pair = jj & 31;
  const int kvh = g & 7, b = g >> 3;
  const int tid = threadIdx.x;
  const int lane = tid & 63, w = tid >> 6;
  const int lr = lane & 15, lg = lane >> 4;
  const int h = kvh * 4 + w;

  __shared__ __align__(16) unsigned short Ksm[64 * 136];   // [key][d], pad +8
  __shared__ __align__(16) unsigned short Vsm[128 * 72];   // [d][key], pad +8
  __shared__ __align__(16) unsigned short Psm[4][32 * 72]; // per-wave [q][key], pad +8
  __shared__ float Alds[4][32];

  const float SL2E = 0.1275378504229740f;  // (1/sqrt(128)) * log2(e)

  const unsigned short* Kb0 = QKV + (size_t)(b * SLEN) * QKVLD + 4096 + kvh * HD;
  const unsigned short* VTb = VTm + ((size_t)(b * NKV + kvh) * HD) * SLEN;

#pragma unroll 1
  for (int halfq = 0; halfq < 2; ++halfq) {
    const int qt = halfq ? (63 - pair) : pair;
    const int q0 = qt * 32;
    const int ntiles = (qt >> 1) + 1;

    // Q fragments: q = ni*16+lr, d = kd*32+lg*8
    bf16x8 qf[2][4];
    const unsigned short* Qb = QKV + (size_t)(b * SLEN + q0) * QKVLD + h * HD;
#pragma unroll
    for (int ni = 0; ni < 2; ++ni)
#pragma unroll
      for (int kd = 0; kd < 4; ++kd)
        qf[ni][kd] = *(const bf16x8*)&Qb[(size_t)(ni * 16 + lr) * QKVLD + kd * 32 + lg * 8];

    f32x4 acc_o[2][8] = {};
    float m_run[2] = {-1e30f, -1e30f};
    float l_run[2] = {0.f, 0.f};

    // prefetch tile 0 -> regs
    bf16x8 kreg[4], vreg[4];
#pragma unroll
    for (int i = 0; i < 4; ++i) {
      int c = tid + i * 256;
      kreg[i] = *(const bf16x8*)&Kb0[(size_t)(c >> 4) * QKVLD + (c & 15) * 8];
      vreg[i] = *(const bf16x8*)&VTb[(size_t)(c >> 3) * SLEN + (c & 7) * 8];
    }

#pragma unroll 1
    for (int t = 0; t < ntiles; ++t) {
      const int kv0 = t * 64;
      __syncthreads();
#pragma unroll
      for (int i = 0; i < 4; ++i) {
        int c = tid + i * 256;
        *(bf16x8*)&Ksm[(c >> 4) * 136 + (c & 15) * 8] = kreg[i];
        *(bf16x8*)&Vsm[(c >> 3) * 72 + (c & 7) * 8] = vreg[i];
      }
      __syncthreads();

      if (t + 1 < ntiles) {
#pragma unroll
        for (int i = 0; i < 4; ++i) {
          int c = tid + i * 256;
          kreg[i] = *(const bf16x8*)&Kb0[(size_t)(kv0 + 64 + (c >> 4)) * QKVLD + (c & 15) * 8];
          vreg[i] = *(const bf16x8*)&VTb[(size_t)(c >> 3) * SLEN + kv0 + 64 + (c & 7) * 8];
        }
      }

      // QK^T: S^T(64 key x 32 q) = K @ Q^T
      f32x4 accs[4][2] = {};
#pragma unroll
      for (int kd = 0; kd < 4; ++kd) {
        bf16x8 kf[4];
#pragma unroll
        for (int mi = 0; mi < 4; ++mi)
          kf[mi] = *(const bf16x8*)&Ksm[(mi * 16 + lr) * 136 + kd * 32 + lg * 8];
        __builtin_amdgcn_s_setprio(1);
#pragma unroll
        for (int mi = 0; mi < 4; ++mi)
#pragma unroll
          for (int ni = 0; ni < 2; ++ni)
            accs[mi][ni] =
                __builtin_amdgcn_mfma_f32_16x16x32_bf16(kf[mi], qf[ni][kd], accs[mi][ni], 0, 0, 0);
        __builtin_amdgcn_s_setprio(0);
      }

      // online softmax, log2*scale domain
      const bool domask = (t == ntiles - 1);
      float alpha[2];
#pragma unroll
      for (int ni = 0; ni < 2; ++ni) {
        float cmax = -1e30f;
#pragma unroll
        for (int mi = 0; mi < 4; ++mi)
#pragma unroll
          for (int r = 0; r < 4; ++r) {
            float s = accs[mi][ni][r] * SL2E;
            if (domask) {
              int key = kv0 + mi * 16 + lg * 4 + r;
              int qq = q0 + ni * 16 + lr;
              if (key > qq) s = -1e30f;
            }
            accs[mi][ni][r] = s;
            cmax = fmaxf(cmax, s);
          }
        cmax = fmaxf(cmax, __shfl_xor(cmax, 16));
        cmax = fmaxf(cmax, __shfl_xor(cmax, 32));
        float mnew = fmaxf(m_run[ni], cmax);
        alpha[ni] = exp2f(m_run[ni] - mnew);
        float psum = 0.f;
#pragma unroll
        for (int mi = 0; mi < 4; ++mi)
#pragma unroll
          for (int r = 0; r < 4; ++r) {
            float p = exp2f(accs[mi][ni][r] - mnew);
            accs[mi][ni][r] = p;
            psum += p;
          }
        psum += __shfl_xor(psum, 16);
        psum += __shfl_xor(psum, 32);
        l_run[ni] = l_run[ni] * alpha[ni] + psum;
        m_run[ni] = mnew;
      }

      // exact defer-rescale: skip when running max unchanged (alpha==1)
      if (__any(alpha[0] < 1.f) || __any(alpha[1] < 1.f)) {
        if (lg == 0) { Alds[w][lr] = alpha[0]; Alds[w][16 + lr] = alpha[1]; }
        f32x4 al0 = *(const f32x4*)&Alds[w][lg * 4];
        f32x4 al1 = *(const f32x4*)&Alds[w][16 + lg * 4];
#pragma unroll
        for (int nd = 0; nd < 8; ++nd)
#pragma unroll
          for (int r = 0; r < 4; ++r) {
            acc_o[0][nd][r] *= al0[r];
            acc_o[1][nd][r] *= al1[r];
          }
      }

      // P (S^T: row=key, col=q) -> Psm[q][key] bf16
#pragma unroll
      for (int ni = 0; ni < 2; ++ni)
#pragma unroll
        for (int mi = 0; mi < 4; ++mi)
#pragma unroll
          for (int rp = 0; rp < 4; rp += 2) {
            uint32_t pk = (uint32_t)f2bf(accs[mi][ni][rp]) |
                          ((uint32_t)f2bf(accs[mi][ni][rp + 1]) << 16);
            *(uint32_t*)&Psm[w][(ni * 16 + lr) * 72 + mi * 16 + lg * 4 + rp] = pk;
          }

      // PV: O(32q x 128d) += P(32x64) @ V(64x128)
#pragma unroll
      for (int ks = 0; ks < 2; ++ks) {
        bf16x8 pa[2];
#pragma unroll
        for (int pm = 0; pm < 2; ++pm)
          pa[pm] = *(const bf16x8*)&Psm[w][(pm * 16 + lr) * 72 + ks * 32 + lg * 8];
        __builtin_amdgcn_s_setprio(1);
#pragma unroll
        for (int nd = 0; nd < 8; ++nd) {
          bf16x8 vb = *(const bf16x8*)&Vsm[(nd * 16 + lr) * 72 + ks * 32 + lg * 8];
#pragma unroll
          for (int pm = 0; pm < 2; ++pm)
            acc_o[pm][nd] =
                __builtin_amdgcn_mfma_f32_16x16x32_bf16(pa[pm], vb, acc_o[pm][nd], 0, 0, 0);
        }
        __builtin_amdgcn_s_setprio(0);
      }
    }

    // epilogue: O /= l, store bf16 at (b, q, h, d)
    if (lg == 0) {
      Alds[w][lr] = 1.f / l_run[0];
      Alds[w][16 + lr] = 1.f / l_run[1];
    }
    f32x4 li0 = *(const f32x4*)&Alds[w][lg * 4];
    f32x4 li1 = *(const f32x4*)&Alds[w][16 + lg * 4];
    unsigned short* Ob = Om + ((size_t)(b * SLEN + q0) * NH + h) * HD;
#pragma unroll
    for (int pm = 0; pm < 2; ++pm)
#pragma unroll
      for (int nd = 0; nd < 8; ++nd)
#pragma unroll
        for (int r = 0; r < 4; ++r) {
          int qq = pm * 16 + lg * 4 + r;
          float v = acc_o[pm][nd][r] * (pm ? li1[r] : li0[r]);
          Ob[(size_t)qq * (NH * HD) + nd * 16 + lr] = f2bf(v);
        }
  }
}

// ---------------------------------------------------------------------------
// Launcher.  d_in: hidden, attention_mask(unused: known causal), wq, wk, wv, wo
// Workspace (169 MB): Xbf 32 | Wqkv 48 | QKV 48 | Ob 32 | VTb 8 | ct/st 1
// ---------------------------------------------------------------------------
extern "C" void kernel_launch(void* const* d_in, const int* in_sizes, int n_in,
                              void* d_out, int out_size, void* d_ws, size_t ws_size,
                              hipStream_t stream) {
  const float* hidden = (const float*)d_in[0];
  const float* wq = (const float*)d_in[2];
  const float* wk = (const float*)d_in[3];
  const float* wv = (const float*)d_in[4];
  const float* wo = (const float*)d_in[5];

  char* ws = (char*)d_ws;
  const size_t MB = 1ull << 20;
  unsigned short* Xbf  = (unsigned short*)(ws);             // 32 MB (B*S,4096)
  unsigned short* Wqkv = (unsigned short*)(ws + 32 * MB);   // 48 MB (6144,4096) packed W
  unsigned short* QKV  = (unsigned short*)(ws + 80 * MB);   // 48 MB (B*S,6144)
  unsigned short* Ob   = (unsigned short*)(ws + 128 * MB);  // 32 MB (B*S,4096)
  unsigned short* VTb  = (unsigned short*)(ws + 160 * MB);  // 8 MB (B,8,128,S)
  float* ct = (float*)(ws + 168 * MB);                      // 0.5 MB
  float* st = (float*)(ws + 168 * MB + 524288);             // 0.5 MB

  // 1) bf16 casts (weights packed: Wq rows 0..4095, Wk 4096..5119, Wv 5120..6143)
  cvt_f32_bf16<<<8192, 256, 0, stream>>>(hidden, Xbf);
  cvt_f32_bf16<<<8192, 256, 0, stream>>>(wq, Wqkv);
  cvt_f32_bf16<<<2048, 256, 0, stream>>>(wk, Wqkv + (size_t)4096 * 4096);
  cvt_f32_bf16<<<2048, 256, 0, stream>>>(wv, Wqkv + (size_t)5120 * 4096);

  // 2) fused QKV projection: (4096,4096) @ (6144,4096)^T -> (4096,6144)
  gemm_bt256<unsigned short><<<384, 512, 0, stream>>>(Xbf, Wqkv, QKV, 4096, 6144, 4096);

  // 3) RoPE on Q and K columns of fused buffer
  rope_tables<<<512, 256, 0, stream>>>(ct, st);
  rope_apply<<<4096, 256, 0, stream>>>(QKV, QKVLD, ct, st, NH);
  rope_apply<<<1024, 256, 0, stream>>>(QKV + 4096, QKVLD, ct, st, NKV);

  // 4) V -> V^T
  transpose_v<<<dim3(64, 16), 256, 0, stream>>>(QKV + 5120, QKVLD, VTb);

  // 5) causal GQA flash attention (paired q-tiles, XCD-grouped)
  attn_fwd<<<512, 256, 0, stream>>>(QKV, VTb, Ob);

  // 6) output projection (fp32 out); Wqkv region reused for Wo
  cvt_f32_bf16<<<8192, 256, 0, stream>>>(wo, Wqkv);
  gemm_bt256<float><<<256, 512, 0, stream>>>(Ob, Wqkv, (float*)d_out, 4096, 4096, 4096);
}

// Round 5
// 575.699 us; speedup vs baseline: 1.3731x; 1.0441x over previous
//
#include <hip/hip_runtime.h>
#include <hip/hip_bf16.h>
#include <stdint.h>

// ---------------------------------------------------------------------------
// GroupedQueryAttention: hidden(B,S,4096) -> fused QKV proj -> RoPE -> causal
// GQA flash attention -> out proj.  B=2 S=2048 H=32 Hk=8 D=128.  bf16 MFMA.
// ---------------------------------------------------------------------------

#define HIDDEN 4096
#define NH 32
#define NKV 8
#define HD 128
#define SLEN 2048
#define BATCH 2
#define QKVLD 6144  // fused QKV row stride (cols: Q 0..4095, K 4096..5119, V 5120..6143)

typedef __attribute__((ext_vector_type(8))) short bf16x8;
typedef __attribute__((ext_vector_type(4))) float f32x4;

__device__ __forceinline__ unsigned short f2bf(float f) {
  __hip_bfloat16 h = __float2bfloat16(f);
  return *reinterpret_cast<unsigned short*>(&h);
}
__device__ __forceinline__ float bf2f(unsigned short h) {
  union { uint32_t u; float f; } v; v.u = ((uint32_t)h) << 16;
  return v.f;
}
__device__ __forceinline__ void gload_lds16(const void* g, void* l) {
  __builtin_amdgcn_global_load_lds(
      (const __attribute__((address_space(1))) unsigned int*)g,
      (__attribute__((address_space(3))) unsigned int*)l, 16, 0, 0);
}

// ---------------------------------------------------------------------------
// fp32 -> bf16 convert, 8 elems/thread. n = grid*2048 exactly.
// ---------------------------------------------------------------------------
__global__ __launch_bounds__(256) void cvt_f32_bf16(const float* __restrict__ in,
                                                    unsigned short* __restrict__ out) {
  size_t i = ((size_t)blockIdx.x * 256 + threadIdx.x) * 8;
  f32x4 a = *(const f32x4*)&in[i];
  f32x4 b = *(const f32x4*)&in[i + 4];
  bf16x8 o;
#pragma unroll
  for (int j = 0; j < 4; ++j) { o[j] = (short)f2bf(a[j]); o[4 + j] = (short)f2bf(b[j]); }
  *(bf16x8*)&out[i] = o;
}

// ---------------------------------------------------------------------------
// GEMM  C(M,N) = A(M,K) @ B(N,K)^T, bf16 in, OutT out.
// 256x256 tile, BK=32, 8 waves (2x4 -> 128x64 each), 512 threads.
// 4-deep LDS pipeline (4 x 32KB K-tile buffers = 128 KiB), counted vmcnt (T4).
// T2 swizzle (rule #21 both-sides): LDS chunk row*4+cc holds global column-
// chunk cc ^ ((row>>1)&3).  Staging keeps LDS dest linear and pre-swizzles the
// GLOBAL source column; frag reads XOR the same term.  Frag-read bank-quad
// slot = (lr&1)*4 + (lg ^ ((lr>>1)&3)) -> 8 lanes/quad (2/bank, free) for
// every 16-lane group -> conflict-free ds_read_b128.
// M,N multiples of 256; K multiple of 32 (>=96); grid % 8 == 0.
// ---------------------------------------------------------------------------
__device__ __forceinline__ void store_out(unsigned short* C, size_t i, float v) { C[i] = f2bf(v); }
__device__ __forceinline__ void store_out(float* C, size_t i, float v) { C[i] = v; }

template <typename OutT>
__global__ __launch_bounds__(512, 2)
void gemm_bt256(const unsigned short* __restrict__ A, const unsigned short* __restrict__ B,
                OutT* __restrict__ C, int M, int N, int K) {
  // 4 buffers x (A: 1024 chunks | B: 1024 chunks), chunk = 16B = 8 bf16
  __shared__ __align__(16) unsigned short lds[4 * 2048 * 8];

  const int tid = threadIdx.x;
  const int lane = tid & 63, w = tid >> 6;
  const int lr = lane & 15, lg = lane >> 4;
  const int wr = w >> 2, wc = w & 3;  // 2 x 4 wave grid
  const int rsw = (lr >> 1) & 3;      // read-side swizzle term (row-derived)

  const int nbn = N >> 8;
  const int nwg = gridDim.x;
  int wg = (int)blockIdx.x;
  wg = (wg & 7) * (nwg >> 3) + (wg >> 3);  // XCD-aware swizzle (nwg%8==0)
  const int bm = wg / nbn, bn = wg % nbn;

  const unsigned short* Ab = A + (size_t)bm * 256 * K;
  const unsigned short* Bb = B + (size_t)bn * 256 * K;

  f32x4 acc[8][4] = {};

  // stage one K-tile (A 16KB + B 16KB) into buf[t&3]: 4 gload_lds16/thread.
  // LDS dest linear (chunk idx = tid + j*512); global source column-chunk
  // pre-swizzled: scc = (idx&3) ^ ((row>>1)&3), row = idx>>2.
  auto stage = [&](int t2) {
    const int kt = t2 * 32;
    unsigned short* lb = lds + (size_t)(t2 & 3) * 2048 * 8;
#pragma unroll
    for (int j = 0; j < 2; ++j) {
      int idx = tid + j * 512;
      int scc = (idx & 3) ^ ((idx >> 3) & 3);
      gload_lds16(Ab + (size_t)(idx >> 2) * K + kt + scc * 8,
                  lb + (size_t)(w * 64 + j * 512) * 8);
    }
#pragma unroll
    for (int j = 0; j < 2; ++j) {
      int idx = tid + j * 512;
      int scc = (idx & 3) ^ ((idx >> 3) & 3);
      gload_lds16(Bb + (size_t)(idx >> 2) * K + kt + scc * 8,
                  lb + (size_t)(1024 + w * 64 + j * 512) * 8);
    }
  };

  const int NT = K >> 5;

  // prologue: fill 3 tiles ahead; wait tile 0 only (vmcnt(8): t1,t2 in flight)
  stage(0);
  stage(1);
  stage(2);
  asm volatile("s_waitcnt vmcnt(8)" ::: "memory");
  __builtin_amdgcn_s_barrier();
  asm volatile("" ::: "memory");

#pragma unroll 1
  for (int t = 0; t < NT; ++t) {
    if (t + 3 < NT) stage(t + 3);

    const unsigned short* bufp = lds + (size_t)(t & 3) * 2048 * 8;
    bf16x8 af[8], bfv[4];
#pragma unroll
    for (int mi = 0; mi < 8; ++mi)
      af[mi] = *(const bf16x8*)&bufp[(size_t)(wr * 512 + mi * 64 + lr * 4 + (lg ^ rsw)) * 8];
#pragma unroll
    for (int ni = 0; ni < 4; ++ni)
      bfv[ni] = *(const bf16x8*)&bufp[(size_t)(1024 + wc * 256 + ni * 64 + lr * 4 + (lg ^ rsw)) * 8];

    __builtin_amdgcn_s_setprio(1);
#pragma unroll
    for (int mi = 0; mi < 8; ++mi)
#pragma unroll
      for (int ni = 0; ni < 4; ++ni)
        acc[mi][ni] = __builtin_amdgcn_mfma_f32_16x16x32_bf16(af[mi], bfv[ni], acc[mi][ni], 0, 0, 0);
    __builtin_amdgcn_s_setprio(0);

    if (t + 1 < NT) {
      if (t + 3 < NT)      asm volatile("s_waitcnt vmcnt(8)" ::: "memory");
      else if (t + 2 < NT) asm volatile("s_waitcnt vmcnt(4)" ::: "memory");
      else                 asm volatile("s_waitcnt vmcnt(0)" ::: "memory");
      __builtin_amdgcn_s_barrier();
      asm volatile("" ::: "memory");
    }
  }

#pragma unroll
  for (int mi = 0; mi < 8; ++mi)
#pragma unroll
    for (int ni = 0; ni < 4; ++ni)
#pragma unroll
      for (int r = 0; r < 4; ++r) {
        size_t row = (size_t)bm * 256 + wr * 128 + mi * 16 + lg * 4 + r;
        size_t col = (size_t)bn * 256 + wc * 64 + ni * 16 + lr;
        store_out(C, row * N + col, acc[mi][ni][r]);
      }
}

// ---------------------------------------------------------------------------
// RoPE tables + apply
// ---------------------------------------------------------------------------
__global__ __launch_bounds__(256) void rope_tables(float* __restrict__ ct, float* __restrict__ st) {
  int idx = blockIdx.x * 256 + threadIdx.x;  // S*64
  int s = idx >> 6, j = idx & 63;
  float inv = exp2f(-(float)j * (13.287712379549449f / 64.f));
  float f = (float)s * inv;
  ct[idx] = cosf(f);
  st[idx] = sinf(f);
}

__global__ __launch_bounds__(256) void rope_apply(unsigned short* __restrict__ X, int ld,
                                                  const float* __restrict__ ct,
                                                  const float* __restrict__ st, int heads) {
  int idx = blockIdx.x * 256 + threadIdx.x;
  int jc = (idx & 7) * 8;
  int t2 = idx >> 3;
  int hh = t2 % heads;
  int row = t2 / heads;
  int s = row & (SLEN - 1);
  unsigned short* p = X + (size_t)row * ld + hh * HD;
  bf16x8 lo = *(bf16x8*)&p[jc];
  bf16x8 hi = *(bf16x8*)&p[64 + jc];
  bf16x8 nlo, nhi;
#pragma unroll
  for (int j = 0; j < 8; ++j) {
    float c = ct[s * 64 + jc + j];
    float sn = st[s * 64 + jc + j];
    float xl = bf2f((unsigned short)(lo[j]));
    float xh = bf2f((unsigned short)(hi[j]));
    nlo[j] = (short)f2bf(xl * c - xh * sn);
    nhi[j] = (short)f2bf(xh * c + xl * sn);
  }
  *(bf16x8*)&p[jc] = nlo;
  *(bf16x8*)&p[64 + jc] = nhi;
}

// ---------------------------------------------------------------------------
// V (rows B*S at stride ld, 1024 cols) -> VT (B, NKV, HD, S)
// ---------------------------------------------------------------------------
__global__ __launch_bounds__(256) void transpose_v(const unsigned short* __restrict__ Vsrc, int ld,
                                                   unsigned short* __restrict__ VT) {
  __shared__ unsigned short tile[64][66];
  const int t = threadIdx.x;
  const int bs = blockIdx.x;
  const int bd = blockIdx.y;
  const int b = bs >> 5;
  const int s0 = (bs & 31) * 64;
  const int d0 = bd * 64;
#pragma unroll
  for (int it = 0; it < 2; ++it) {
    int si = (t >> 3) + it * 32;
    int dj = (t & 7) * 8;
    bf16x8 v = *(const bf16x8*)&Vsrc[(size_t)(b * SLEN + s0 + si) * ld + d0 + dj];
#pragma unroll
    for (int j = 0; j < 8; ++j) tile[si][dj + j] = (unsigned short)(v[j]);
  }
  __syncthreads();
#pragma unroll
  for (int it = 0; it < 2; ++it) {
    int di = (t >> 3) + it * 32;
    int sj = (t & 7) * 8;
    bf16x8 o;
#pragma unroll
    for (int j = 0; j < 8; ++j) o[j] = (short)tile[sj + j][di];
    int c = d0 + di;
    int kvh = c >> 7, d = c & 127;
    *(bf16x8*)&VT[(((size_t)b * NKV + kvh) * HD + d) * SLEN + s0 + sj] = o;
  }
}

// ---------------------------------------------------------------------------
// Flash attention (round-3 version, validated).
// ---------------------------------------------------------------------------
__global__ __launch_bounds__(256, 2)
void attn_fwd(const unsigned short* __restrict__ QKV, const unsigned short* __restrict__ VTm,
              unsigned short* __restrict__ Om) {
  const int blk = blockIdx.x;            // 0..511
  const int xcd = blk & 7, jj = blk >> 3;
  const int g = xcd + ((jj >> 5) << 3);  // (b,kvh) group 0..15, pinned per XCD
  const int pair = jj & 31;
  const int kvh = g & 7, b = g >> 3;
  const int tid = threadIdx.x;
  const int lane = tid & 63, w = tid >> 6;
  const int lr = lane & 15, lg = lane >> 4;
  const int h = kvh * 4 + w;

  __shared__ __align__(16) unsigned short Ksm[64 * 136];   // [key][d], pad +8
  __shared__ __align__(16) unsigned short Vsm[128 * 72];   // [d][key], pad +8
  __shared__ __align__(16) unsigned short Psm[4][32 * 72]; // per-wave [q][key], pad +8
  __shared__ float Alds[4][32];

  const float SL2E = 0.1275378504229740f;  // (1/sqrt(128)) * log2(e)

  const unsigned short* Kb0 = QKV + (size_t)(b * SLEN) * QKVLD + 4096 + kvh * HD;
  const unsigned short* VTb = VTm + ((size_t)(b * NKV + kvh) * HD) * SLEN;

#pragma unroll 1
  for (int halfq = 0; halfq < 2; ++halfq) {
    const int qt = halfq ? (63 - pair) : pair;
    const int q0 = qt * 32;
    const int ntiles = (qt >> 1) + 1;

    // Q fragments: q = ni*16+lr, d = kd*32+lg*8
    bf16x8 qf[2][4];
    const unsigned short* Qb = QKV + (size_t)(b * SLEN + q0) * QKVLD + h * HD;
#pragma unroll
    for (int ni = 0; ni < 2; ++ni)
#pragma unroll
      for (int kd = 0; kd < 4; ++kd)
        qf[ni][kd] = *(const bf16x8*)&Qb[(size_t)(ni * 16 + lr) * QKVLD + kd * 32 + lg * 8];

    f32x4 acc_o[2][8] = {};
    float m_run[2] = {-1e30f, -1e30f};
    float l_run[2] = {0.f, 0.f};

    // prefetch tile 0 -> regs
    bf16x8 kreg[4], vreg[4];
#pragma unroll
    for (int i = 0; i < 4; ++i) {
      int c = tid + i * 256;
      kreg[i] = *(const bf16x8*)&Kb0[(size_t)(c >> 4) * QKVLD + (c & 15) * 8];
      vreg[i] = *(const bf16x8*)&VTb[(size_t)(c >> 3) * SLEN + (c & 7) * 8];
    }

#pragma unroll 1
    for (int t = 0; t < ntiles; ++t) {
      const int kv0 = t * 64;
      __syncthreads();
#pragma unroll
      for (int i = 0; i < 4; ++i) {
        int c = tid + i * 256;
        *(bf16x8*)&Ksm[(c >> 4) * 136 + (c & 15) * 8] = kreg[i];
        *(bf16x8*)&Vsm[(c >> 3) * 72 + (c & 7) * 8] = vreg[i];
      }
      __syncthreads();

      if (t + 1 < ntiles) {
#pragma unroll
        for (int i = 0; i < 4; ++i) {
          int c = tid + i * 256;
          kreg[i] = *(const bf16x8*)&Kb0[(size_t)(kv0 + 64 + (c >> 4)) * QKVLD + (c & 15) * 8];
          vreg[i] = *(const bf16x8*)&VTb[(size_t)(c >> 3) * SLEN + kv0 + 64 + (c & 7) * 8];
        }
      }

      // QK^T: S^T(64 key x 32 q) = K @ Q^T
      f32x4 accs[4][2] = {};
#pragma unroll
      for (int kd = 0; kd < 4; ++kd) {
        bf16x8 kf[4];
#pragma unroll
        for (int mi = 0; mi < 4; ++mi)
          kf[mi] = *(const bf16x8*)&Ksm[(mi * 16 + lr) * 136 + kd * 32 + lg * 8];
        __builtin_amdgcn_s_setprio(1);
#pragma unroll
        for (int mi = 0; mi < 4; ++mi)
#pragma unroll
          for (int ni = 0; ni < 2; ++ni)
            accs[mi][ni] =
                __builtin_amdgcn_mfma_f32_16x16x32_bf16(kf[mi], qf[ni][kd], accs[mi][ni], 0, 0, 0);
        __builtin_amdgcn_s_setprio(0);
      }

      // online softmax, log2*scale domain
      const bool domask = (t == ntiles - 1);
      float alpha[2];
#pragma unroll
      for (int ni = 0; ni < 2; ++ni) {
        float cmax = -1e30f;
#pragma unroll
        for (int mi = 0; mi < 4; ++mi)
#pragma unroll
          for (int r = 0; r < 4; ++r) {
            float s = accs[mi][ni][r] * SL2E;
            if (domask) {
              int key = kv0 + mi * 16 + lg * 4 + r;
              int qq = q0 + ni * 16 + lr;
              if (key > qq) s = -1e30f;
            }
            accs[mi][ni][r] = s;
            cmax = fmaxf(cmax, s);
          }
        cmax = fmaxf(cmax, __shfl_xor(cmax, 16));
        cmax = fmaxf(cmax, __shfl_xor(cmax, 32));
        float mnew = fmaxf(m_run[ni], cmax);
        alpha[ni] = exp2f(m_run[ni] - mnew);
        float psum = 0.f;
#pragma unroll
        for (int mi = 0; mi < 4; ++mi)
#pragma unroll
          for (int r = 0; r < 4; ++r) {
            float p = exp2f(accs[mi][ni][r] - mnew);
            accs[mi][ni][r] = p;
            psum += p;
          }
        psum += __shfl_xor(psum, 16);
        psum += __shfl_xor(psum, 32);
        l_run[ni] = l_run[ni] * alpha[ni] + psum;
        m_run[ni] = mnew;
      }

      // exact defer-rescale: skip when running max unchanged (alpha==1)
      if (__any(alpha[0] < 1.f) || __any(alpha[1] < 1.f)) {
        if (lg == 0) { Alds[w][lr] = alpha[0]; Alds[w][16 + lr] = alpha[1]; }
        f32x4 al0 = *(const f32x4*)&Alds[w][lg * 4];
        f32x4 al1 = *(const f32x4*)&Alds[w][16 + lg * 4];
#pragma unroll
        for (int nd = 0; nd < 8; ++nd)
#pragma unroll
          for (int r = 0; r < 4; ++r) {
            acc_o[0][nd][r] *= al0[r];
            acc_o[1][nd][r] *= al1[r];
          }
      }

      // P (S^T: row=key, col=q) -> Psm[q][key] bf16
#pragma unroll
      for (int ni = 0; ni < 2; ++ni)
#pragma unroll
        for (int mi = 0; mi < 4; ++mi)
#pragma unroll
          for (int rp = 0; rp < 4; rp += 2) {
            uint32_t pk = (uint32_t)f2bf(accs[mi][ni][rp]) |
                          ((uint32_t)f2bf(accs[mi][ni][rp + 1]) << 16);
            *(uint32_t*)&Psm[w][(ni * 16 + lr) * 72 + mi * 16 + lg * 4 + rp] = pk;
          }

      // PV: O(32q x 128d) += P(32x64) @ V(64x128)
#pragma unroll
      for (int ks = 0; ks < 2; ++ks) {
        bf16x8 pa[2];
#pragma unroll
        for (int pm = 0; pm < 2; ++pm)
          pa[pm] = *(const bf16x8*)&Psm[w][(pm * 16 + lr) * 72 + ks * 32 + lg * 8];
        __builtin_amdgcn_s_setprio(1);
#pragma unroll
        for (int nd = 0; nd < 8; ++nd) {
          bf16x8 vb = *(const bf16x8*)&Vsm[(nd * 16 + lr) * 72 + ks * 32 + lg * 8];
#pragma unroll
          for (int pm = 0; pm < 2; ++pm)
            acc_o[pm][nd] =
                __builtin_amdgcn_mfma_f32_16x16x32_bf16(pa[pm], vb, acc_o[pm][nd], 0, 0, 0);
        }
        __builtin_amdgcn_s_setprio(0);
      }
    }

    // epilogue: O /= l, store bf16 at (b, q, h, d)
    if (lg == 0) {
      Alds[w][lr] = 1.f / l_run[0];
      Alds[w][16 + lr] = 1.f / l_run[1];
    }
    f32x4 li0 = *(const f32x4*)&Alds[w][lg * 4];
    f32x4 li1 = *(const f32x4*)&Alds[w][16 + lg * 4];
    unsigned short* Ob = Om + ((size_t)(b * SLEN + q0) * NH + h) * HD;
#pragma unroll
    for (int pm = 0; pm < 2; ++pm)
#pragma unroll
      for (int nd = 0; nd < 8; ++nd)
#pragma unroll
        for (int r = 0; r < 4; ++r) {
          int qq = pm * 16 + lg * 4 + r;
          float v = acc_o[pm][nd][r] * (pm ? li1[r] : li0[r]);
          Ob[(size_t)qq * (NH * HD) + nd * 16 + lr] = f2bf(v);
        }
  }
}

// ---------------------------------------------------------------------------
// Launcher.  d_in: hidden, attention_mask(unused: known causal), wq, wk, wv, wo
// Workspace (169 MB): Xbf 32 | Wqkv 48 | QKV 48 | Ob 32 | VTb 8 | ct/st 1
// ---------------------------------------------------------------------------
extern "C" void kernel_launch(void* const* d_in, const int* in_sizes, int n_in,
                              void* d_out, int out_size, void* d_ws, size_t ws_size,
                              hipStream_t stream) {
  const float* hidden = (const float*)d_in[0];
  const float* wq = (const float*)d_in[2];
  const float* wk = (const float*)d_in[3];
  const float* wv = (const float*)d_in[4];
  const float* wo = (const float*)d_in[5];

  char* ws = (char*)d_ws;
  const size_t MB = 1ull << 20;
  unsigned short* Xbf  = (unsigned short*)(ws);             // 32 MB (B*S,4096)
  unsigned short* Wqkv = (unsigned short*)(ws + 32 * MB);   // 48 MB (6144,4096) packed W
  unsigned short* QKV  = (unsigned short*)(ws + 80 * MB);   // 48 MB (B*S,6144)
  unsigned short* Ob   = (unsigned short*)(ws + 128 * MB);  // 32 MB (B*S,4096)
  unsigned short* VTb  = (unsigned short*)(ws + 160 * MB);  // 8 MB (B,8,128,S)
  float* ct = (float*)(ws + 168 * MB);                      // 0.5 MB
  float* st = (float*)(ws + 168 * MB + 524288);             // 0.5 MB

  // 1) bf16 casts (weights packed: Wq rows 0..4095, Wk 4096..5119, Wv 5120..6143)
  cvt_f32_bf16<<<8192, 256, 0, stream>>>(hidden, Xbf);
  cvt_f32_bf16<<<8192, 256, 0, stream>>>(wq, Wqkv);
  cvt_f32_bf16<<<2048, 256, 0, stream>>>(wk, Wqkv + (size_t)4096 * 4096);
  cvt_f32_bf16<<<2048, 256, 0, stream>>>(wv, Wqkv + (size_t)5120 * 4096);

  // 2) fused QKV projection: (4096,4096) @ (6144,4096)^T -> (4096,6144)
  gemm_bt256<unsigned short><<<384, 512, 0, stream>>>(Xbf, Wqkv, QKV, 4096, 6144, 4096);

  // 3) RoPE on Q and K columns of fused buffer
  rope_tables<<<512, 256, 0, stream>>>(ct, st);
  rope_apply<<<4096, 256, 0, stream>>>(QKV, QKVLD, ct, st, NH);
  rope_apply<<<1024, 256, 0, stream>>>(QKV + 4096, QKVLD, ct, st, NKV);

  // 4) V -> V^T
  transpose_v<<<dim3(64, 16), 256, 0, stream>>>(QKV + 5120, QKVLD, VTb);

  // 5) causal GQA flash attention (paired q-tiles, XCD-grouped)
  attn_fwd<<<512, 256, 0, stream>>>(QKV, VTb, Ob);

  // 6) output projection (fp32 out); Wqkv region reused for Wo
  cvt_f32_bf16<<<8192, 256, 0, stream>>>(wo, Wqkv);
  gemm_bt256<float><<<256, 512, 0, stream>>>(Ob, Wqkv, (float*)d_out, 4096, 4096, 4096);
}